// Round 11
// baseline (823.419 us; speedup 1.0000x reference)
//
#include <hip/hip_runtime.h>
#include <hip/hip_bf16.h>
#include <math.h>

#define NN 100000
#define EE 800000
#define FIN 256
#define CH 64      // HID
#define C1 256     // H*HID
#define BN_EPS 1e-5f
#define NEG_SLOPE 0.2f

typedef __attribute__((ext_vector_type(8))) short short8;
typedef __attribute__((ext_vector_type(8))) unsigned short u16x8;
typedef __attribute__((ext_vector_type(4))) float f32x4;

__device__ __forceinline__ float bf2f(ushort u) {
    return __uint_as_float(((unsigned)u) << 16);
}
__device__ __forceinline__ ushort f2bf(float f) {
    unsigned u = __float_as_uint(f);
    return (ushort)((u + 0x7FFF + ((u >> 16) & 1)) >> 16);   // RNE
}

// ================= CSR build =================
__global__ void hist_kernel(const int* __restrict__ ei, int* __restrict__ deg) {
    int t = blockIdx.x * 256 + threadIdx.x;
    if (t < EE) atomicAdd(&deg[ei[EE + t]], 1);
}
// scan over deg+1; also emits dinv = rsqrt(deg+1)
__global__ void scan_k1(const int* __restrict__ deg, int* __restrict__ row_start,
                        int* __restrict__ bsum, float* __restrict__ dinv) {
    __shared__ int sh[256];
    int t = threadIdx.x;
    int i = blockIdx.x * 256 + t;
    int v = (i < NN) ? (deg[i] + 1) : 0;
    if (i < NN) dinv[i] = rsqrtf((float)v);
    sh[t] = v;
    __syncthreads();
    for (int off = 1; off < 256; off <<= 1) {
        int add = (t >= off) ? sh[t - off] : 0;
        __syncthreads();
        sh[t] += add;
        __syncthreads();
    }
    if (i < NN) row_start[i] = sh[t] - v;
    if (t == 255) bsum[blockIdx.x] = sh[255];
}
__global__ void scan_k2(int* __restrict__ bsum, int nb) {
    __shared__ int sh[512];
    int t = threadIdx.x;
    int v = (t < nb) ? bsum[t] : 0;
    sh[t] = v;
    __syncthreads();
    for (int off = 1; off < 512; off <<= 1) {
        int add = (t >= off) ? sh[t - off] : 0;
        __syncthreads();
        sh[t] += add;
        __syncthreads();
    }
    if (t < nb) bsum[t] = sh[t] - v;
}
__global__ void scan_k3(int* __restrict__ row_start, const int* __restrict__ bsum) {
    int i = blockIdx.x * 256 + threadIdx.x;
    if (i < NN) row_start[i] += bsum[i >> 8];
    if (i == NN) row_start[NN] = EE + NN;
}
__global__ void scatter_kernel(const int* __restrict__ ei, const int* __restrict__ row_start,
                               int* __restrict__ fill, int* __restrict__ sorted) {
    int t = blockIdx.x * 256 + threadIdx.x;
    if (t >= EE + NN) return;
    int s, d;
    if (t < EE) { s = ei[t]; d = ei[EE + t]; }
    else        { s = t - EE; d = s; }
    int pos = atomicAdd(&fill[d], 1);
    sorted[row_start[d] + pos] = s;
}

// ================= weight conversions (all three in one dispatch) =========
__global__ void transpose_all(const float* __restrict__ Wg, const float* __restrict__ W1,
                              const float* __restrict__ W2, ushort* __restrict__ Wgt,
                              ushort* __restrict__ W1t, ushort* __restrict__ W2t) {
    int idx = blockIdx.x * 256 + threadIdx.x;
    if (idx < FIN * CH) {                       // Wg [FIN][CH] -> Wgt [CH][FIN]
        int m = idx / CH, n = idx % CH;
        Wgt[n * FIN + m] = f2bf(Wg[idx]);
    } else if (idx < FIN * CH + CH * C1) {      // W1 [CH][C1] -> W1t [C1][CH]
        int i = idx - FIN * CH;
        int m = i / C1, n = i % C1;
        W1t[n * CH + m] = f2bf(W1[i]);
    } else if (idx < FIN * CH + CH * C1 + C1 * C1) {
        int i = idx - FIN * CH - CH * C1;       // W2 [C1][C1] -> W2t [C1][C1]
        int m = i / C1, n = i % C1;
        W2t[n * C1 + m] = f2bf(W2[i]);
    }
}

// ====== bf16 MFMA GEMM (templated A-load, NCOLB col-blocks, fused alpha) ==
// C[N x K] = A[N x M] @ B[M x K]; Bt bf16 [K][M]. grid (K/(64*NCOLB), N/64).
// AMODE 1: A fp32, plain convert (GEMM1).
// AMODE 2: A fp32 agg; value = bf16(scale*relu(a+bias)+shift)   (GCN BN apply)
// AMODE 3: A bf16 y;  value = bf16(elu(scale*y+shift))          (GAT BN apply)
// NCOLB=4 processes all 256 output cols per block: A read ONCE, transform 1x.
// If alpha_s != null: col-frag cf belongs to head cf>>2 (colBase==0, K==256).
template<int AMODE, int NCOLB>
__global__ __launch_bounds__(256) void gemm_mfma(
        const void* __restrict__ Ap, const ushort* __restrict__ Bt,
        ushort* __restrict__ C, int M, int K,
        const float* __restrict__ t_bias, const float* __restrict__ t_scale,
        const float* __restrict__ t_shift,
        const float* __restrict__ a_src, const float* __restrict__ a_dst,
        float* __restrict__ alpha_s, float* __restrict__ alpha_d) {
    __shared__ ushort As[64][40];
    __shared__ ushort Bs[64 * NCOLB][40];
    int t = threadIdx.x;
    int w = t >> 6;
    int l = t & 63;
    int rowBase = blockIdx.y * 64;
    int colBase = blockIdx.x * 64 * NCOLB;
    int srow = t >> 2;
    int sk = (t & 3) * 8;
    int m = l & 15, q = l >> 4;
    f32x4 acc[4 * NCOLB] = {};
    for (int k0 = 0; k0 < M; k0 += 32) {
        int gr = rowBase + srow;
        int ch = k0 + sk;
        ushort4 u0 = {0, 0, 0, 0}, u1 = {0, 0, 0, 0};
        if (AMODE == 1) {
            if (gr < NN) {
                const float* Af = (const float*)Ap;
                float4 f0 = *(const float4*)&Af[(long)gr * M + ch];
                float4 f1 = *(const float4*)&Af[(long)gr * M + ch + 4];
                u0.x = f2bf(f0.x); u0.y = f2bf(f0.y); u0.z = f2bf(f0.z); u0.w = f2bf(f0.w);
                u1.x = f2bf(f1.x); u1.y = f2bf(f1.y); u1.z = f2bf(f1.z); u1.w = f2bf(f1.w);
            }
        } else if (AMODE == 2) {
            if (gr < NN) {
                const float* Af = (const float*)Ap;
                float4 f0 = *(const float4*)&Af[(long)gr * M + ch];
                float4 f1 = *(const float4*)&Af[(long)gr * M + ch + 4];
                f32x4 b0 = *(const f32x4*)&t_bias[ch],  b1 = *(const f32x4*)&t_bias[ch + 4];
                f32x4 s0 = *(const f32x4*)&t_scale[ch], s1 = *(const f32x4*)&t_scale[ch + 4];
                f32x4 h0 = *(const f32x4*)&t_shift[ch], h1 = *(const f32x4*)&t_shift[ch + 4];
                u0.x = f2bf(s0[0] * fmaxf(f0.x + b0[0], 0.f) + h0[0]);
                u0.y = f2bf(s0[1] * fmaxf(f0.y + b0[1], 0.f) + h0[1]);
                u0.z = f2bf(s0[2] * fmaxf(f0.z + b0[2], 0.f) + h0[2]);
                u0.w = f2bf(s0[3] * fmaxf(f0.w + b0[3], 0.f) + h0[3]);
                u1.x = f2bf(s1[0] * fmaxf(f1.x + b1[0], 0.f) + h1[0]);
                u1.y = f2bf(s1[1] * fmaxf(f1.y + b1[1], 0.f) + h1[1]);
                u1.z = f2bf(s1[2] * fmaxf(f1.z + b1[2], 0.f) + h1[2]);
                u1.w = f2bf(s1[3] * fmaxf(f1.w + b1[3], 0.f) + h1[3]);
            }
        } else { // AMODE == 3
            if (gr < NN) {
                const ushort* Ab = (const ushort*)Ap;
                u16x8 y = *(const u16x8*)&Ab[(long)gr * M + ch];
                f32x4 s0 = *(const f32x4*)&t_scale[ch], s1 = *(const f32x4*)&t_scale[ch + 4];
                f32x4 h0 = *(const f32x4*)&t_shift[ch], h1 = *(const f32x4*)&t_shift[ch + 4];
                float r[8];
#pragma unroll
                for (int j = 0; j < 8; ++j) {
                    float sc = (j < 4) ? s0[j] : s1[j - 4];
                    float sh = (j < 4) ? h0[j] : h1[j - 4];
                    float v = sc * bf2f((ushort)y[j]) + sh;
                    r[j] = (v > 0.f) ? v : (__expf(v) - 1.f);
                }
                u0.x = f2bf(r[0]); u0.y = f2bf(r[1]); u0.z = f2bf(r[2]); u0.w = f2bf(r[3]);
                u1.x = f2bf(r[4]); u1.y = f2bf(r[5]); u1.z = f2bf(r[6]); u1.w = f2bf(r[7]);
            }
        }
        *(ushort4*)&As[srow][sk] = u0;
        *(ushort4*)&As[srow][sk + 4] = u1;
#pragma unroll
        for (int cb = 0; cb < NCOLB; ++cb) {
            uint4 bv = *(const uint4*)&Bt[(long)(colBase + cb * 64 + srow) * M + k0 + sk];
            *(uint4*)&Bs[cb * 64 + srow][sk] = bv;
        }
        __syncthreads();
        short8 af = *(const short8*)&As[w * 16 + m][q * 8];
#pragma unroll
        for (int cf = 0; cf < 4 * NCOLB; ++cf) {
            short8 bf = *(const short8*)&Bs[cf * 16 + m][q * 8];
            acc[cf] = __builtin_amdgcn_mfma_f32_16x16x32_bf16(af, bf, acc[cf], 0, 0, 0);
        }
        __syncthreads();
    }
    if (alpha_s) {
        float ps[4][4] = {}, pd[4][4] = {};
#pragma unroll
        for (int cf = 0; cf < 4 * NCOLB; ++cf) {
            int hh = cf >> 2;
            float av = a_src[colBase + cf * 16 + m];
            float dv = a_dst[colBase + cf * 16 + m];
#pragma unroll
            for (int r = 0; r < 4; ++r) {
                ps[hh][r] += acc[cf][r] * av;
                pd[hh][r] += acc[cf][r] * dv;
            }
        }
#pragma unroll
        for (int hh = 0; hh < 4; ++hh) {
#pragma unroll
            for (int r = 0; r < 4; ++r) {
                ps[hh][r] += __shfl_xor(ps[hh][r], 1); pd[hh][r] += __shfl_xor(pd[hh][r], 1);
                ps[hh][r] += __shfl_xor(ps[hh][r], 2); pd[hh][r] += __shfl_xor(pd[hh][r], 2);
                ps[hh][r] += __shfl_xor(ps[hh][r], 4); pd[hh][r] += __shfl_xor(pd[hh][r], 4);
                ps[hh][r] += __shfl_xor(ps[hh][r], 8); pd[hh][r] += __shfl_xor(pd[hh][r], 8);
            }
        }
        if (m == 0) {
#pragma unroll
            for (int r = 0; r < 4; ++r) {
                int row = rowBase + w * 16 + q * 4 + r;
                if (row < NN) {
#pragma unroll
                    for (int hh = 0; hh < 4; ++hh) {
                        alpha_s[row * 4 + hh] = ps[hh][r];
                        alpha_d[row * 4 + hh] = pd[hh][r];
                    }
                }
            }
        }
    }
#pragma unroll
    for (int cf = 0; cf < 4 * NCOLB; ++cf) {
#pragma unroll
        for (int r = 0; r < 4; ++r) {
            int orow = rowBase + w * 16 + q * 4 + r;
            if (orow < NN) C[(long)orow * K + colBase + cf * 16 + m] = f2bf(acc[cf][r]);
        }
    }
}

// ================= GCN gather =================
__global__ __launch_bounds__(256) void gcn_gather(
        const int* __restrict__ row_start, const int* __restrict__ sorted,
        const float* __restrict__ dinv, const ushort* __restrict__ h0,
        float* __restrict__ agg) {
    int node = blockIdx.x * 4 + (threadIdx.x >> 6);
    if (node >= NN) return;
    int l = threadIdx.x & 63;
    int slot = l >> 3;          // edge slot 0..7
    int li = l & 7;             // lane within row
    int c = li * 8;             // 8 channels of 64
    int b = row_start[node], e = row_start[node + 1];
    float a[8] = {};
    for (int i = b + slot; i < e; i += 8) {
        int s = sorted[i];
        float dv = dinv[s];
        u16x8 v = *(const u16x8*)&h0[(long)s * 64 + c];
#pragma unroll
        for (int j = 0; j < 8; ++j) a[j] += dv * bf2f((ushort)v[j]);
    }
#pragma unroll
    for (int j = 0; j < 8; ++j) {
        a[j] += __shfl_xor(a[j], 8);
        a[j] += __shfl_xor(a[j], 16);
        a[j] += __shfl_xor(a[j], 32);
    }
    if (slot == 0) {
        float dn = dinv[node];
        f32x4 o0, o1;
#pragma unroll
        for (int j = 0; j < 4; ++j) { o0[j] = a[j] * dn; o1[j] = a[4 + j] * dn; }
        *(f32x4*)&agg[(long)node * 64 + c] = o0;
        *(f32x4*)&agg[(long)node * 64 + c + 4] = o1;
    }
}

// ================= BatchNorm =================
__global__ __launch_bounds__(256) void bn_stats64(
        const float* __restrict__ x, const float* __restrict__ bias,
        float* __restrict__ sums, float* __restrict__ sumsq) {
    __shared__ float red[4][16][8];
    int l = threadIdx.x & 63;
    int w = threadIdx.x >> 6;
    int wv = blockIdx.x * 4 + w;
    int nw = gridDim.x * 4;
    int sub = l >> 4;
    int c = (l & 15) * 4;
    f32x4 b4 = *(const f32x4*)&bias[c];
    float s0 = 0.f, s1 = 0.f, s2 = 0.f, s3 = 0.f;
    float q0 = 0.f, q1 = 0.f, q2 = 0.f, q3 = 0.f;
    for (int r = wv * 4 + sub; r < NN; r += nw * 4) {
        f32x4 v = *(const f32x4*)&x[(long)r * 64 + c];
        float v0 = fmaxf(v[0] + b4[0], 0.f);
        float v1 = fmaxf(v[1] + b4[1], 0.f);
        float v2 = fmaxf(v[2] + b4[2], 0.f);
        float v3 = fmaxf(v[3] + b4[3], 0.f);
        s0 += v0; s1 += v1; s2 += v2; s3 += v3;
        q0 += v0 * v0; q1 += v1 * v1; q2 += v2 * v2; q3 += v3 * v3;
    }
    s0 += __shfl_xor(s0, 16); s1 += __shfl_xor(s1, 16);
    s2 += __shfl_xor(s2, 16); s3 += __shfl_xor(s3, 16);
    q0 += __shfl_xor(q0, 16); q1 += __shfl_xor(q1, 16);
    q2 += __shfl_xor(q2, 16); q3 += __shfl_xor(q3, 16);
    s0 += __shfl_xor(s0, 32); s1 += __shfl_xor(s1, 32);
    s2 += __shfl_xor(s2, 32); s3 += __shfl_xor(s3, 32);
    q0 += __shfl_xor(q0, 32); q1 += __shfl_xor(q1, 32);
    q2 += __shfl_xor(q2, 32); q3 += __shfl_xor(q3, 32);
    if (sub == 0) {
        int li = l & 15;
        red[w][li][0] = s0; red[w][li][1] = s1; red[w][li][2] = s2; red[w][li][3] = s3;
        red[w][li][4] = q0; red[w][li][5] = q1; red[w][li][6] = q2; red[w][li][7] = q3;
    }
    __syncthreads();
    if (w == 0 && sub == 0) {
        int li = l & 15;
        atomicAdd(&sums[c + 0], red[0][li][0] + red[1][li][0] + red[2][li][0] + red[3][li][0]);
        atomicAdd(&sums[c + 1], red[0][li][1] + red[1][li][1] + red[2][li][1] + red[3][li][1]);
        atomicAdd(&sums[c + 2], red[0][li][2] + red[1][li][2] + red[2][li][2] + red[3][li][2]);
        atomicAdd(&sums[c + 3], red[0][li][3] + red[1][li][3] + red[2][li][3] + red[3][li][3]);
        atomicAdd(&sumsq[c + 0], red[0][li][4] + red[1][li][4] + red[2][li][4] + red[3][li][4]);
        atomicAdd(&sumsq[c + 1], red[0][li][5] + red[1][li][5] + red[2][li][5] + red[3][li][5]);
        atomicAdd(&sumsq[c + 2], red[0][li][6] + red[1][li][6] + red[2][li][6] + red[3][li][6]);
        atomicAdd(&sumsq[c + 3], red[0][li][7] + red[1][li][7] + red[2][li][7] + red[3][li][7]);
    }
}
__global__ __launch_bounds__(256) void bn_stats256(
        const ushort* __restrict__ x,
        float* __restrict__ sums, float* __restrict__ sumsq) {
    __shared__ float red[4][64][8];
    int l = threadIdx.x & 63;
    int w = threadIdx.x >> 6;
    int wv = blockIdx.x * 4 + w;
    int nw = gridDim.x * 4;
    int c = l * 4;
    float s0 = 0.f, s1 = 0.f, s2 = 0.f, s3 = 0.f;
    float q0 = 0.f, q1 = 0.f, q2 = 0.f, q3 = 0.f;
    for (int r = wv; r < NN; r += nw) {
        ushort4 v = *(const ushort4*)&x[(long)r * 256 + c];
        float v0 = bf2f(v.x), v1 = bf2f(v.y), v2 = bf2f(v.z), v3 = bf2f(v.w);
        s0 += v0; s1 += v1; s2 += v2; s3 += v3;
        q0 += v0 * v0; q1 += v1 * v1; q2 += v2 * v2; q3 += v3 * v3;
    }
    red[w][l][0] = s0; red[w][l][1] = s1; red[w][l][2] = s2; red[w][l][3] = s3;
    red[w][l][4] = q0; red[w][l][5] = q1; red[w][l][6] = q2; red[w][l][7] = q3;
    __syncthreads();
    if (w == 0) {
        atomicAdd(&sums[c + 0], red[0][l][0] + red[1][l][0] + red[2][l][0] + red[3][l][0]);
        atomicAdd(&sums[c + 1], red[0][l][1] + red[1][l][1] + red[2][l][1] + red[3][l][1]);
        atomicAdd(&sums[c + 2], red[0][l][2] + red[1][l][2] + red[2][l][2] + red[3][l][2]);
        atomicAdd(&sums[c + 3], red[0][l][3] + red[1][l][3] + red[2][l][3] + red[3][l][3]);
        atomicAdd(&sumsq[c + 0], red[0][l][4] + red[1][l][4] + red[2][l][4] + red[3][l][4]);
        atomicAdd(&sumsq[c + 1], red[0][l][5] + red[1][l][5] + red[2][l][5] + red[3][l][5]);
        atomicAdd(&sumsq[c + 2], red[0][l][6] + red[1][l][6] + red[2][l][6] + red[3][l][6]);
        atomicAdd(&sumsq[c + 3], red[0][l][7] + red[1][l][7] + red[2][l][7] + red[3][l][7]);
    }
}
__global__ void bn_finalize(const float* __restrict__ sums, const float* __restrict__ sumsq,
                            const float* __restrict__ g, const float* __restrict__ beta,
                            float* __restrict__ scale, float* __restrict__ shift, int C) {
    int c = threadIdx.x;
    if (c < C) {
        float mean = sums[c] / (float)NN;
        float var = sumsq[c] / (float)NN - mean * mean;
        float sc = g[c] * rsqrtf(var + BN_EPS);
        scale[c] = sc;
        shift[c] = beta[c] - mean * sc;
    }
}
// GAT BN apply, fp32 out (final layer only; bias cancels).
__global__ __launch_bounds__(256) void bn_apply_gat(
        const ushort* __restrict__ x,
        const float* __restrict__ scale, const float* __restrict__ shift,
        float* __restrict__ out) {
    int l = threadIdx.x & 63;
    int wv = blockIdx.x * 4 + (threadIdx.x >> 6);
    int nw = gridDim.x * 4;
    int c = l * 4;
    f32x4 sc4 = *(const f32x4*)&scale[c];
    f32x4 sh4 = *(const f32x4*)&shift[c];
    for (int r = wv; r < NN; r += nw) {
        ushort4 v = *(const ushort4*)&x[(long)r * 256 + c];
        float t0 = sc4[0] * bf2f(v.x) + sh4[0];
        float t1 = sc4[1] * bf2f(v.y) + sh4[1];
        float t2 = sc4[2] * bf2f(v.z) + sh4[2];
        float t3 = sc4[3] * bf2f(v.w) + sh4[3];
        f32x4 o;
        o[0] = (t0 > 0.f) ? t0 : (__expf(t0) - 1.f);
        o[1] = (t1 > 0.f) ? t1 : (__expf(t1) - 1.f);
        o[2] = (t2 > 0.f) ? t2 : (__expf(t2) - 1.f);
        o[3] = (t3 > 0.f) ? t3 : (__expf(t3) - 1.f);
        *(f32x4*)&out[(long)r * 256 + c] = o;
    }
}

// ========== FUSED GAT attention+gather ==========
__global__ __launch_bounds__(256) void gat_gather(
        const int* __restrict__ row_start, const int* __restrict__ sorted,
        const float* __restrict__ as, const float* __restrict__ ad,
        const ushort* __restrict__ h, ushort* __restrict__ out) {
    int node = blockIdx.x * 4 + (threadIdx.x >> 6);
    if (node >= NN) return;
    int l = threadIdx.x & 63;
    int head = l >> 4;                      // channels 4l..4l+3 share one head
    int b = row_start[node], e = row_start[node + 1];
    float adn = ad[node * 4 + head];
    float a0 = 0.f, a1 = 0.f, a2 = 0.f, a3 = 0.f;
    float ls = 0.f;
    int i = b;
    for (; i + 3 < e; i += 4) {
        int s[4]; float ev[4]; ushort4 v[4];
#pragma unroll
        for (int j = 0; j < 4; ++j) s[j] = sorted[i + j];
#pragma unroll
        for (int j = 0; j < 4; ++j) ev[j] = as[s[j] * 4 + head];
#pragma unroll
        for (int j = 0; j < 4; ++j) v[j] = *(const ushort4*)&h[(long)s[j] * 256 + l * 4];
#pragma unroll
        for (int j = 0; j < 4; ++j) {
            float t = ev[j] + adn;
            t = (t > 0.f) ? t : NEG_SLOPE * t;
            float wt = __expf(t);
            ls += wt;
            a0 += wt * bf2f(v[j].x);
            a1 += wt * bf2f(v[j].y);
            a2 += wt * bf2f(v[j].z);
            a3 += wt * bf2f(v[j].w);
        }
    }
    for (; i < e; ++i) {
        int sv = sorted[i];
        float t = as[sv * 4 + head] + adn;
        t = (t > 0.f) ? t : NEG_SLOPE * t;
        float wt = __expf(t);
        ushort4 v0 = *(const ushort4*)&h[(long)sv * 256 + l * 4];
        ls += wt;
        a0 += wt * bf2f(v0.x);
        a1 += wt * bf2f(v0.y);
        a2 += wt * bf2f(v0.z);
        a3 += wt * bf2f(v0.w);
    }
    float inv = 1.0f / ls;
    ushort4 o;
    o.x = f2bf(a0 * inv);
    o.y = f2bf(a1 * inv);
    o.z = f2bf(a2 * inv);
    o.w = f2bf(a3 * inv);
    *(ushort4*)&out[(long)node * 256 + l * 4] = o;
}

// ================= launch =================
extern "C" void kernel_launch(void* const* d_in, const int* in_sizes, int n_in,
                              void* d_out, int out_size, void* d_ws, size_t ws_size,
                              hipStream_t stream) {
    const float* x      = (const float*)d_in[0];
    const int*   ei     = (const int*)d_in[1];
    const float* W_gcn  = (const float*)d_in[2];
    const float* b_gcn  = (const float*)d_in[3];
    const float* g0     = (const float*)d_in[4];
    const float* beta0  = (const float*)d_in[5];
    const float* W1     = (const float*)d_in[6];
    const float* a_src1 = (const float*)d_in[7];
    const float* a_dst1 = (const float*)d_in[8];
    const float* b1     = (const float*)d_in[9];
    const float* g1     = (const float*)d_in[10];
    const float* beta1  = (const float*)d_in[11];
    const float* W2     = (const float*)d_in[12];
    const float* a_src2 = (const float*)d_in[13];
    const float* a_dst2 = (const float*)d_in[14];
    const float* b2     = (const float*)d_in[15];
    const float* g2     = (const float*)d_in[16];
    const float* beta2  = (const float*)d_in[17];

    const long N = NN;
    float* ws = (float*)d_ws;

    // ---- layout ----
    float* dinv    = ws;                        // N
    float* alpha_s = ws + N;                    // 4N
    float* alpha_d = ws + 5 * N;                // 4N
    float* sums0   = ws + 9 * N;                // 64
    float* sumsq0  = sums0 + 64;                // 64
    float* sums1   = sumsq0 + 64;               // 256
    float* sumsq1  = sums1 + 256;               // 256
    float* sums2   = sumsq1 + 256;              // 256
    float* sumsq2  = sums2 + 256;               // 256  (stats region = 1152 floats)
    float* scale   = sumsq2 + 256;              // 256
    float* shift   = scale + 256;               // 256
    int*   row_start = (int*)(shift + 256);     // N+1
    int*   fill      = row_start + NN + 1;      // N
    int*   deg_i     = fill + NN;               // N
    int*   sorted    = deg_i + NN;              // 9N
    int*   bsum      = sorted + EE + NN;        // ~400
    ushort* Wgt  = (ushort*)(ws + 23 * N);      // 64x256
    ushort* W1t  = Wgt + 16384;                 // 256x64
    ushort* W2t  = W1t + 16384;                 // 256x256
    ushort* h0b  = (ushort*)(ws + 24 * N);      // [N,64] bf16
    float*  agg0 = ws + 56 * N;                 // [N,64] fp32
    ushort* h1b  = (ushort*)(ws + 120 * N);     // [N,256] bf16; also h2
    ushort* yb   = (ushort*)(ws + 376 * N);     // [N,256] bf16 gather out
    float*  outp = (float*)d_out;

    const int BLK = 256;
    dim3 blk(BLK);
    const int NBLK_N = (NN + 255) / 256;        // 391

    // ===== CSR build =====
    hipMemsetAsync(fill, 0, 2L * NN * sizeof(int), stream);
    hipMemsetAsync(sums0, 0, 1152 * sizeof(float), stream);
    hist_kernel<<<(EE + 255) / 256, blk, 0, stream>>>(ei, deg_i);
    scan_k1<<<NBLK_N, blk, 0, stream>>>(deg_i, row_start, bsum, dinv);
    scan_k2<<<1, 512, 0, stream>>>(bsum, NBLK_N);
    scan_k3<<<(NN + 1 + 255) / 256, blk, 0, stream>>>(row_start, bsum);
    scatter_kernel<<<(EE + NN + 255) / 256, blk, 0, stream>>>(ei, row_start, fill, sorted);

    // ===== weight conversions (one dispatch) =====
    transpose_all<<<(FIN * CH + CH * C1 + C1 * C1 + 255) / 256, blk, 0, stream>>>(
        W_gcn, W1, W2, Wgt, W1t, W2t);

    // ===== GCN =====
    gemm_mfma<1, 1><<<dim3(1, (NN + 63) / 64), blk, 0, stream>>>(
        x, Wgt, h0b, FIN, CH, nullptr, nullptr, nullptr,
        nullptr, nullptr, nullptr, nullptr);
    gcn_gather<<<(NN + 3) / 4, blk, 0, stream>>>(row_start, sorted, dinv, h0b, agg0);
    bn_stats64<<<512, blk, 0, stream>>>(agg0, b_gcn, sums0, sumsq0);
    bn_finalize<<<1, CH, 0, stream>>>(sums0, sumsq0, g0, beta0, scale, shift, CH);

    // ===== GAT layer 1 (BN-apply fused into A-load; alpha fused; 1 col pass) =====
    gemm_mfma<2, 4><<<dim3(1, (NN + 63) / 64), blk, 0, stream>>>(
        agg0, W1t, h1b, CH, C1, b_gcn, scale, shift,
        a_src1, a_dst1, alpha_s, alpha_d);
    gat_gather<<<(NN + 3) / 4, blk, 0, stream>>>(row_start, sorted, alpha_s, alpha_d, h1b, yb);
    bn_stats256<<<512, blk, 0, stream>>>(yb, sums1, sumsq1);
    bn_finalize<<<1, C1, 0, stream>>>(sums1, sumsq1, g1, beta1, scale, shift, C1);

    // ===== GAT layer 2 (BN+ELU fused into A-load; alpha fused; 1 col pass) =====
    gemm_mfma<3, 4><<<dim3(1, (NN + 63) / 64), blk, 0, stream>>>(
        yb, W2t, h1b, C1, C1, nullptr, scale, shift,
        a_src2, a_dst2, alpha_s, alpha_d);
    gat_gather<<<(NN + 3) / 4, blk, 0, stream>>>(row_start, sorted, alpha_s, alpha_d, h1b, yb);
    bn_stats256<<<512, blk, 0, stream>>>(yb, sums2, sumsq2);
    bn_finalize<<<1, C1, 0, stream>>>(sums2, sumsq2, g2, beta2, scale, shift, C1);
    bn_apply_gat<<<2048, blk, 0, stream>>>(yb, scale, shift, outp);
}

// Round 13
// 787.240 us; speedup vs baseline: 1.0460x; 1.0460x over previous
//
#include <hip/hip_runtime.h>
#include <hip/hip_bf16.h>
#include <math.h>

#define NN 100000
#define EE 800000
#define FIN 256
#define CH 64      // HID
#define C1 256     // H*HID
#define BN_EPS 1e-5f
#define NEG_SLOPE 0.2f

typedef __attribute__((ext_vector_type(8))) short short8;
typedef __attribute__((ext_vector_type(8))) unsigned short u16x8;
typedef __attribute__((ext_vector_type(4))) float f32x4;

__device__ __forceinline__ float bf2f(ushort u) {
    return __uint_as_float(((unsigned)u) << 16);
}
__device__ __forceinline__ ushort f2bf(float f) {
    unsigned u = __float_as_uint(f);
    return (ushort)((u + 0x7FFF + ((u >> 16) & 1)) >> 16);   // RNE
}

// ================= CSR build =================
__global__ void hist_kernel(const int* __restrict__ ei, int* __restrict__ deg) {
    int t = blockIdx.x * 256 + threadIdx.x;
    if (t < EE) atomicAdd(&deg[ei[EE + t]], 1);
}
// scan over deg+1; also emits dinv = rsqrt(deg+1)
__global__ void scan_k1(const int* __restrict__ deg, int* __restrict__ row_start,
                        int* __restrict__ bsum, float* __restrict__ dinv) {
    __shared__ int sh[256];
    int t = threadIdx.x;
    int i = blockIdx.x * 256 + t;
    int v = (i < NN) ? (deg[i] + 1) : 0;
    if (i < NN) dinv[i] = rsqrtf((float)v);
    sh[t] = v;
    __syncthreads();
    for (int off = 1; off < 256; off <<= 1) {
        int add = (t >= off) ? sh[t - off] : 0;
        __syncthreads();
        sh[t] += add;
        __syncthreads();
    }
    if (i < NN) row_start[i] = sh[t] - v;
    if (t == 255) bsum[blockIdx.x] = sh[255];
}
__global__ void scan_k2(int* __restrict__ bsum, int nb) {
    __shared__ int sh[512];
    int t = threadIdx.x;
    int v = (t < nb) ? bsum[t] : 0;
    sh[t] = v;
    __syncthreads();
    for (int off = 1; off < 512; off <<= 1) {
        int add = (t >= off) ? sh[t - off] : 0;
        __syncthreads();
        sh[t] += add;
        __syncthreads();
    }
    if (t < nb) bsum[t] = sh[t] - v;
}
__global__ void scan_k3(int* __restrict__ row_start, const int* __restrict__ bsum) {
    int i = blockIdx.x * 256 + threadIdx.x;
    if (i < NN) row_start[i] += bsum[i >> 8];
    if (i == NN) row_start[NN] = EE + NN;
}
__global__ void scatter_kernel(const int* __restrict__ ei, const int* __restrict__ row_start,
                               int* __restrict__ fill, int* __restrict__ sorted) {
    int t = blockIdx.x * 256 + threadIdx.x;
    if (t >= EE + NN) return;
    int s, d;
    if (t < EE) { s = ei[t]; d = ei[EE + t]; }
    else        { s = t - EE; d = s; }
    int pos = atomicAdd(&fill[d], 1);
    sorted[row_start[d] + pos] = s;
}

// ================= weight conversions (all three in one dispatch) =========
__global__ void transpose_all(const float* __restrict__ Wg, const float* __restrict__ W1,
                              const float* __restrict__ W2, ushort* __restrict__ Wgt,
                              ushort* __restrict__ W1t, ushort* __restrict__ W2t) {
    int idx = blockIdx.x * 256 + threadIdx.x;
    if (idx < FIN * CH) {                       // Wg [FIN][CH] -> Wgt [CH][FIN]
        int m = idx / CH, n = idx % CH;
        Wgt[n * FIN + m] = f2bf(Wg[idx]);
    } else if (idx < FIN * CH + CH * C1) {      // W1 [CH][C1] -> W1t [C1][CH]
        int i = idx - FIN * CH;
        int m = i / C1, n = i % C1;
        W1t[n * CH + m] = f2bf(W1[i]);
    } else if (idx < FIN * CH + CH * C1 + C1 * C1) {
        int i = idx - FIN * CH - CH * C1;       // W2 [C1][C1] -> W2t [C1][C1]
        int m = i / C1, n = i % C1;
        W2t[n * C1 + m] = f2bf(W2[i]);
    }
}

// ====== bf16 MFMA GEMM (templated A-load, fused GAT alpha) ==
// C[N x K] = A[N x M] @ B[M x K]; Bt bf16 [K][M]. grid (K/64, N/64).
// AMODE 1: A fp32, plain convert (GEMM1).
// AMODE 2: A fp32 agg; value = bf16(scale*relu(a+bias)+shift)   (GCN BN apply)
// AMODE 3: A bf16 y;  value = bf16(elu(scale*y+shift))          (GAT BN apply)
// If alpha_s != null: col-block == head (K==256); fused alpha dot + store.
template<int AMODE>
__global__ __launch_bounds__(256) void gemm_mfma(
        const void* __restrict__ Ap, const ushort* __restrict__ Bt,
        ushort* __restrict__ C, int M, int K,
        const float* __restrict__ t_bias, const float* __restrict__ t_scale,
        const float* __restrict__ t_shift,
        const float* __restrict__ a_src, const float* __restrict__ a_dst,
        float* __restrict__ alpha_s, float* __restrict__ alpha_d) {
    __shared__ ushort As[64][40];
    __shared__ ushort Bs[64][40];
    int t = threadIdx.x;
    int w = t >> 6;
    int l = t & 63;
    int rowBase = blockIdx.y * 64;
    int colBase = blockIdx.x * 64;
    int srow = t >> 2;
    int sk = (t & 3) * 8;
    int m = l & 15, q = l >> 4;
    f32x4 acc[4] = {};
    for (int k0 = 0; k0 < M; k0 += 32) {
        int gr = rowBase + srow;
        int ch = k0 + sk;
        ushort4 u0 = {0, 0, 0, 0}, u1 = {0, 0, 0, 0};
        if (AMODE == 1) {
            if (gr < NN) {
                const float* Af = (const float*)Ap;
                float4 f0 = *(const float4*)&Af[(long)gr * M + ch];
                float4 f1 = *(const float4*)&Af[(long)gr * M + ch + 4];
                u0.x = f2bf(f0.x); u0.y = f2bf(f0.y); u0.z = f2bf(f0.z); u0.w = f2bf(f0.w);
                u1.x = f2bf(f1.x); u1.y = f2bf(f1.y); u1.z = f2bf(f1.z); u1.w = f2bf(f1.w);
            }
        } else if (AMODE == 2) {
            if (gr < NN) {
                const float* Af = (const float*)Ap;
                float4 f0 = *(const float4*)&Af[(long)gr * M + ch];
                float4 f1 = *(const float4*)&Af[(long)gr * M + ch + 4];
                f32x4 b0 = *(const f32x4*)&t_bias[ch],  b1 = *(const f32x4*)&t_bias[ch + 4];
                f32x4 s0 = *(const f32x4*)&t_scale[ch], s1 = *(const f32x4*)&t_scale[ch + 4];
                f32x4 h0 = *(const f32x4*)&t_shift[ch], h1 = *(const f32x4*)&t_shift[ch + 4];
                u0.x = f2bf(s0[0] * fmaxf(f0.x + b0[0], 0.f) + h0[0]);
                u0.y = f2bf(s0[1] * fmaxf(f0.y + b0[1], 0.f) + h0[1]);
                u0.z = f2bf(s0[2] * fmaxf(f0.z + b0[2], 0.f) + h0[2]);
                u0.w = f2bf(s0[3] * fmaxf(f0.w + b0[3], 0.f) + h0[3]);
                u1.x = f2bf(s1[0] * fmaxf(f1.x + b1[0], 0.f) + h1[0]);
                u1.y = f2bf(s1[1] * fmaxf(f1.y + b1[1], 0.f) + h1[1]);
                u1.z = f2bf(s1[2] * fmaxf(f1.z + b1[2], 0.f) + h1[2]);
                u1.w = f2bf(s1[3] * fmaxf(f1.w + b1[3], 0.f) + h1[3]);
            }
        } else { // AMODE == 3
            if (gr < NN) {
                const ushort* Ab = (const ushort*)Ap;
                u16x8 y = *(const u16x8*)&Ab[(long)gr * M + ch];
                f32x4 s0 = *(const f32x4*)&t_scale[ch], s1 = *(const f32x4*)&t_scale[ch + 4];
                f32x4 h0 = *(const f32x4*)&t_shift[ch], h1 = *(const f32x4*)&t_shift[ch + 4];
                float r[8];
#pragma unroll
                for (int j = 0; j < 8; ++j) {
                    float sc = (j < 4) ? s0[j] : s1[j - 4];
                    float sh = (j < 4) ? h0[j] : h1[j - 4];
                    float v = sc * bf2f((ushort)y[j]) + sh;
                    r[j] = (v > 0.f) ? v : (__expf(v) - 1.f);
                }
                u0.x = f2bf(r[0]); u0.y = f2bf(r[1]); u0.z = f2bf(r[2]); u0.w = f2bf(r[3]);
                u1.x = f2bf(r[4]); u1.y = f2bf(r[5]); u1.z = f2bf(r[6]); u1.w = f2bf(r[7]);
            }
        }
        *(ushort4*)&As[srow][sk] = u0;
        *(ushort4*)&As[srow][sk + 4] = u1;
        uint4 bv = *(const uint4*)&Bt[(long)(colBase + srow) * M + k0 + sk];
        *(uint4*)&Bs[srow][sk] = bv;
        __syncthreads();
        short8 af = *(const short8*)&As[w * 16 + m][q * 8];
#pragma unroll
        for (int c = 0; c < 4; ++c) {
            short8 bf = *(const short8*)&Bs[c * 16 + m][q * 8];
            acc[c] = __builtin_amdgcn_mfma_f32_16x16x32_bf16(af, bf, acc[c], 0, 0, 0);
        }
        __syncthreads();
    }
    if (alpha_s) {
        int head = colBase >> 6;
        float ps[4] = {}, pd[4] = {};
#pragma unroll
        for (int c = 0; c < 4; ++c) {
            float av = a_src[colBase + c * 16 + m];
            float dv = a_dst[colBase + c * 16 + m];
#pragma unroll
            for (int r = 0; r < 4; ++r) {
                ps[r] += acc[c][r] * av;
                pd[r] += acc[c][r] * dv;
            }
        }
#pragma unroll
        for (int r = 0; r < 4; ++r) {
            ps[r] += __shfl_xor(ps[r], 1); pd[r] += __shfl_xor(pd[r], 1);
            ps[r] += __shfl_xor(ps[r], 2); pd[r] += __shfl_xor(pd[r], 2);
            ps[r] += __shfl_xor(ps[r], 4); pd[r] += __shfl_xor(pd[r], 4);
            ps[r] += __shfl_xor(ps[r], 8); pd[r] += __shfl_xor(pd[r], 8);
        }
        if (m == 0) {
#pragma unroll
            for (int r = 0; r < 4; ++r) {
                int row = rowBase + w * 16 + q * 4 + r;
                if (row < NN) {
                    alpha_s[row * 4 + head] = ps[r];
                    alpha_d[row * 4 + head] = pd[r];
                }
            }
        }
    }
#pragma unroll
    for (int c = 0; c < 4; ++c) {
#pragma unroll
        for (int r = 0; r < 4; ++r) {
            int orow = rowBase + w * 16 + q * 4 + r;
            if (orow < NN) C[(long)orow * K + colBase + c * 16 + m] = f2bf(acc[c][r]);
        }
    }
}

// ================= GCN gather =================
__global__ __launch_bounds__(256) void gcn_gather(
        const int* __restrict__ row_start, const int* __restrict__ sorted,
        const float* __restrict__ dinv, const ushort* __restrict__ h0,
        float* __restrict__ agg) {
    int node = __builtin_amdgcn_readfirstlane(blockIdx.x * 4 + (threadIdx.x >> 6));
    if (node >= NN) return;
    int l = threadIdx.x & 63;
    int slot = l >> 3;          // edge slot 0..7
    int li = l & 7;             // lane within row
    int c = li * 8;             // 8 channels of 64
    int b = row_start[node], e = row_start[node + 1];
    float a[8] = {};
    for (int i = b + slot; i < e; i += 8) {
        int s = sorted[i];
        float dv = dinv[s];
        u16x8 v = *(const u16x8*)&h0[(long)s * 64 + c];
#pragma unroll
        for (int j = 0; j < 8; ++j) a[j] += dv * bf2f((ushort)v[j]);
    }
#pragma unroll
    for (int j = 0; j < 8; ++j) {
        a[j] += __shfl_xor(a[j], 8);
        a[j] += __shfl_xor(a[j], 16);
        a[j] += __shfl_xor(a[j], 32);
    }
    if (slot == 0) {
        float dn = dinv[node];
        f32x4 o0, o1;
#pragma unroll
        for (int j = 0; j < 4; ++j) { o0[j] = a[j] * dn; o1[j] = a[4 + j] * dn; }
        *(f32x4*)&agg[(long)node * 64 + c] = o0;
        *(f32x4*)&agg[(long)node * 64 + c + 4] = o1;
    }
}

// ================= BatchNorm =================
__global__ __launch_bounds__(256) void bn_stats64(
        const float* __restrict__ x, const float* __restrict__ bias,
        float* __restrict__ sums, float* __restrict__ sumsq) {
    __shared__ float red[4][16][8];
    int l = threadIdx.x & 63;
    int w = threadIdx.x >> 6;
    int wv = blockIdx.x * 4 + w;
    int nw = gridDim.x * 4;
    int sub = l >> 4;
    int c = (l & 15) * 4;
    f32x4 b4 = *(const f32x4*)&bias[c];
    float s0 = 0.f, s1 = 0.f, s2 = 0.f, s3 = 0.f;
    float q0 = 0.f, q1 = 0.f, q2 = 0.f, q3 = 0.f;
    for (int r = wv * 4 + sub; r < NN; r += nw * 4) {
        f32x4 v = *(const f32x4*)&x[(long)r * 64 + c];
        float v0 = fmaxf(v[0] + b4[0], 0.f);
        float v1 = fmaxf(v[1] + b4[1], 0.f);
        float v2 = fmaxf(v[2] + b4[2], 0.f);
        float v3 = fmaxf(v[3] + b4[3], 0.f);
        s0 += v0; s1 += v1; s2 += v2; s3 += v3;
        q0 += v0 * v0; q1 += v1 * v1; q2 += v2 * v2; q3 += v3 * v3;
    }
    s0 += __shfl_xor(s0, 16); s1 += __shfl_xor(s1, 16);
    s2 += __shfl_xor(s2, 16); s3 += __shfl_xor(s3, 16);
    q0 += __shfl_xor(q0, 16); q1 += __shfl_xor(q1, 16);
    q2 += __shfl_xor(q2, 16); q3 += __shfl_xor(q3, 16);
    s0 += __shfl_xor(s0, 32); s1 += __shfl_xor(s1, 32);
    s2 += __shfl_xor(s2, 32); s3 += __shfl_xor(s3, 32);
    q0 += __shfl_xor(q0, 32); q1 += __shfl_xor(q1, 32);
    q2 += __shfl_xor(q2, 32); q3 += __shfl_xor(q3, 32);
    if (sub == 0) {
        int li = l & 15;
        red[w][li][0] = s0; red[w][li][1] = s1; red[w][li][2] = s2; red[w][li][3] = s3;
        red[w][li][4] = q0; red[w][li][5] = q1; red[w][li][6] = q2; red[w][li][7] = q3;
    }
    __syncthreads();
    if (w == 0 && sub == 0) {
        int li = l & 15;
        atomicAdd(&sums[c + 0], red[0][li][0] + red[1][li][0] + red[2][li][0] + red[3][li][0]);
        atomicAdd(&sums[c + 1], red[0][li][1] + red[1][li][1] + red[2][li][1] + red[3][li][1]);
        atomicAdd(&sums[c + 2], red[0][li][2] + red[1][li][2] + red[2][li][2] + red[3][li][2]);
        atomicAdd(&sums[c + 3], red[0][li][3] + red[1][li][3] + red[2][li][3] + red[3][li][3]);
        atomicAdd(&sumsq[c + 0], red[0][li][4] + red[1][li][4] + red[2][li][4] + red[3][li][4]);
        atomicAdd(&sumsq[c + 1], red[0][li][5] + red[1][li][5] + red[2][li][5] + red[3][li][5]);
        atomicAdd(&sumsq[c + 2], red[0][li][6] + red[1][li][6] + red[2][li][6] + red[3][li][6]);
        atomicAdd(&sumsq[c + 3], red[0][li][7] + red[1][li][7] + red[2][li][7] + red[3][li][7]);
    }
}
__global__ __launch_bounds__(256) void bn_stats256(
        const ushort* __restrict__ x,
        float* __restrict__ sums, float* __restrict__ sumsq) {
    __shared__ float red[4][64][8];
    int l = threadIdx.x & 63;
    int w = threadIdx.x >> 6;
    int wv = blockIdx.x * 4 + w;
    int nw = gridDim.x * 4;
    int c = l * 4;
    float s0 = 0.f, s1 = 0.f, s2 = 0.f, s3 = 0.f;
    float q0 = 0.f, q1 = 0.f, q2 = 0.f, q3 = 0.f;
    for (int r = wv; r < NN; r += nw) {
        ushort4 v = *(const ushort4*)&x[(long)r * 256 + c];
        float v0 = bf2f(v.x), v1 = bf2f(v.y), v2 = bf2f(v.z), v3 = bf2f(v.w);
        s0 += v0; s1 += v1; s2 += v2; s3 += v3;
        q0 += v0 * v0; q1 += v1 * v1; q2 += v2 * v2; q3 += v3 * v3;
    }
    red[w][l][0] = s0; red[w][l][1] = s1; red[w][l][2] = s2; red[w][l][3] = s3;
    red[w][l][4] = q0; red[w][l][5] = q1; red[w][l][6] = q2; red[w][l][7] = q3;
    __syncthreads();
    if (w == 0) {
        atomicAdd(&sums[c + 0], red[0][l][0] + red[1][l][0] + red[2][l][0] + red[3][l][0]);
        atomicAdd(&sums[c + 1], red[0][l][1] + red[1][l][1] + red[2][l][1] + red[3][l][1]);
        atomicAdd(&sums[c + 2], red[0][l][2] + red[1][l][2] + red[2][l][2] + red[3][l][2]);
        atomicAdd(&sums[c + 3], red[0][l][3] + red[1][l][3] + red[2][l][3] + red[3][l][3]);
        atomicAdd(&sumsq[c + 0], red[0][l][4] + red[1][l][4] + red[2][l][4] + red[3][l][4]);
        atomicAdd(&sumsq[c + 1], red[0][l][5] + red[1][l][5] + red[2][l][5] + red[3][l][5]);
        atomicAdd(&sumsq[c + 2], red[0][l][6] + red[1][l][6] + red[2][l][6] + red[3][l][6]);
        atomicAdd(&sumsq[c + 3], red[0][l][7] + red[1][l][7] + red[2][l][7] + red[3][l][7]);
    }
}
__global__ void bn_finalize(const float* __restrict__ sums, const float* __restrict__ sumsq,
                            const float* __restrict__ g, const float* __restrict__ beta,
                            float* __restrict__ scale, float* __restrict__ shift, int C) {
    int c = threadIdx.x;
    if (c < C) {
        float mean = sums[c] / (float)NN;
        float var = sumsq[c] / (float)NN - mean * mean;
        float sc = g[c] * rsqrtf(var + BN_EPS);
        scale[c] = sc;
        shift[c] = beta[c] - mean * sc;
    }
}
// GAT BN apply, fp32 out (final layer only; bias cancels).
__global__ __launch_bounds__(256) void bn_apply_gat(
        const ushort* __restrict__ x,
        const float* __restrict__ scale, const float* __restrict__ shift,
        float* __restrict__ out) {
    int l = threadIdx.x & 63;
    int wv = blockIdx.x * 4 + (threadIdx.x >> 6);
    int nw = gridDim.x * 4;
    int c = l * 4;
    f32x4 sc4 = *(const f32x4*)&scale[c];
    f32x4 sh4 = *(const f32x4*)&shift[c];
    for (int r = wv; r < NN; r += nw) {
        ushort4 v = *(const ushort4*)&x[(long)r * 256 + c];
        float t0 = sc4[0] * bf2f(v.x) + sh4[0];
        float t1 = sc4[1] * bf2f(v.y) + sh4[1];
        float t2 = sc4[2] * bf2f(v.z) + sh4[2];
        float t3 = sc4[3] * bf2f(v.w) + sh4[3];
        f32x4 o;
        o[0] = (t0 > 0.f) ? t0 : (__expf(t0) - 1.f);
        o[1] = (t1 > 0.f) ? t1 : (__expf(t1) - 1.f);
        o[2] = (t2 > 0.f) ? t2 : (__expf(t2) - 1.f);
        o[3] = (t3 > 0.f) ? t3 : (__expf(t3) - 1.f);
        *(f32x4*)&out[(long)r * 256 + c] = o;
    }
}

// ========== FUSED GAT attention+gather (scalarized uniform loads) ==========
// One WAVE per node (readfirstlane-uniform). Edge indices + alpha rows load
// via the SMEM pipe (s_load): sorted[i] and as[s*4..3] are wave-uniform;
// per-lane select by head replaces VMEM gathers. Only h-row loads stay VMEM.
__global__ __launch_bounds__(256) void gat_gather(
        const int* __restrict__ row_start, const int* __restrict__ sorted,
        const float* __restrict__ as, const float* __restrict__ ad,
        const ushort* __restrict__ h, ushort* __restrict__ out) {
    int node = __builtin_amdgcn_readfirstlane(blockIdx.x * 4 + (threadIdx.x >> 6));
    if (node >= NN) return;
    int l = threadIdx.x & 63;
    int head = l >> 4;                      // channels 4l..4l+3 share one head
    int b = row_start[node], e = row_start[node + 1];   // uniform -> s_load
    f32x4 ad4 = *(const f32x4*)&ad[node * 4];           // uniform -> s_load x4
    float adn = (head & 2) ? ((head & 1) ? ad4[3] : ad4[2])
                           : ((head & 1) ? ad4[1] : ad4[0]);
    float a0 = 0.f, a1 = 0.f, a2 = 0.f, a3 = 0.f;
    float ls = 0.f;
    int i = b;
    for (; i + 3 < e; i += 4) {
        int s0 = sorted[i];                 // uniform addr -> s_load
        int s1 = sorted[i + 1];
        int s2 = sorted[i + 2];
        int s3 = sorted[i + 3];
        f32x4 e0 = *(const f32x4*)&as[s0 * 4];   // uniform -> s_load_dwordx4
        f32x4 e1 = *(const f32x4*)&as[s1 * 4];
        f32x4 e2 = *(const f32x4*)&as[s2 * 4];
        f32x4 e3 = *(const f32x4*)&as[s3 * 4];
        ushort4 v0 = *(const ushort4*)&h[(long)s0 * 256 + l * 4];
        ushort4 v1 = *(const ushort4*)&h[(long)s1 * 256 + l * 4];
        ushort4 v2 = *(const ushort4*)&h[(long)s2 * 256 + l * 4];
        ushort4 v3 = *(const ushort4*)&h[(long)s3 * 256 + l * 4];
        float ev[4];
        ev[0] = (head & 2) ? ((head & 1) ? e0[3] : e0[2]) : ((head & 1) ? e0[1] : e0[0]);
        ev[1] = (head & 2) ? ((head & 1) ? e1[3] : e1[2]) : ((head & 1) ? e1[1] : e1[0]);
        ev[2] = (head & 2) ? ((head & 1) ? e2[3] : e2[2]) : ((head & 1) ? e2[1] : e2[0]);
        ev[3] = (head & 2) ? ((head & 1) ? e3[3] : e3[2]) : ((head & 1) ? e3[1] : e3[0]);
        float wt[4];
#pragma unroll
        for (int j = 0; j < 4; ++j) {
            float tt = ev[j] + adn;
            tt = (tt > 0.f) ? tt : NEG_SLOPE * tt;
            wt[j] = __expf(tt);
            ls += wt[j];
        }
        a0 += wt[0] * bf2f(v0.x) + wt[1] * bf2f(v1.x) + wt[2] * bf2f(v2.x) + wt[3] * bf2f(v3.x);
        a1 += wt[0] * bf2f(v0.y) + wt[1] * bf2f(v1.y) + wt[2] * bf2f(v2.y) + wt[3] * bf2f(v3.y);
        a2 += wt[0] * bf2f(v0.z) + wt[1] * bf2f(v1.z) + wt[2] * bf2f(v2.z) + wt[3] * bf2f(v3.z);
        a3 += wt[0] * bf2f(v0.w) + wt[1] * bf2f(v1.w) + wt[2] * bf2f(v2.w) + wt[3] * bf2f(v3.w);
    }
    for (; i < e; ++i) {
        int sv = sorted[i];
        f32x4 e0 = *(const f32x4*)&as[sv * 4];
        float ev = (head & 2) ? ((head & 1) ? e0[3] : e0[2]) : ((head & 1) ? e0[1] : e0[0]);
        float tt = ev + adn;
        tt = (tt > 0.f) ? tt : NEG_SLOPE * tt;
        float wt = __expf(tt);
        ushort4 v0 = *(const ushort4*)&h[(long)sv * 256 + l * 4];
        ls += wt;
        a0 += wt * bf2f(v0.x);
        a1 += wt * bf2f(v0.y);
        a2 += wt * bf2f(v0.z);
        a3 += wt * bf2f(v0.w);
    }
    float inv = 1.0f / ls;
    ushort4 o;
    o.x = f2bf(a0 * inv);
    o.y = f2bf(a1 * inv);
    o.z = f2bf(a2 * inv);
    o.w = f2bf(a3 * inv);
    *(ushort4*)&out[(long)node * 256 + l * 4] = o;
}

// ================= launch =================
extern "C" void kernel_launch(void* const* d_in, const int* in_sizes, int n_in,
                              void* d_out, int out_size, void* d_ws, size_t ws_size,
                              hipStream_t stream) {
    const float* x      = (const float*)d_in[0];
    const int*   ei     = (const int*)d_in[1];
    const float* W_gcn  = (const float*)d_in[2];
    const float* b_gcn  = (const float*)d_in[3];
    const float* g0     = (const float*)d_in[4];
    const float* beta0  = (const float*)d_in[5];
    const float* W1     = (const float*)d_in[6];
    const float* a_src1 = (const float*)d_in[7];
    const float* a_dst1 = (const float*)d_in[8];
    const float* b1     = (const float*)d_in[9];
    const float* g1     = (const float*)d_in[10];
    const float* beta1  = (const float*)d_in[11];
    const float* W2     = (const float*)d_in[12];
    const float* a_src2 = (const float*)d_in[13];
    const float* a_dst2 = (const float*)d_in[14];
    const float* b2     = (const float*)d_in[15];
    const float* g2     = (const float*)d_in[16];
    const float* beta2  = (const float*)d_in[17];

    const long N = NN;
    float* ws = (float*)d_ws;

    // ---- layout ----
    float* dinv    = ws;                        // N
    float* alpha_s = ws + N;                    // 4N
    float* alpha_d = ws + 5 * N;                // 4N
    float* sums0   = ws + 9 * N;                // 64
    float* sumsq0  = sums0 + 64;                // 64
    float* sums1   = sumsq0 + 64;               // 256
    float* sumsq1  = sums1 + 256;               // 256
    float* sums2   = sumsq1 + 256;              // 256
    float* sumsq2  = sums2 + 256;               // 256  (stats region = 1152 floats)
    float* scale   = sumsq2 + 256;              // 256
    float* shift   = scale + 256;               // 256
    int*   row_start = (int*)(shift + 256);     // N+1
    int*   fill      = row_start + NN + 1;      // N
    int*   deg_i     = fill + NN;               // N
    int*   sorted    = deg_i + NN;              // 9N
    int*   bsum      = sorted + EE + NN;        // ~400
    ushort* Wgt  = (ushort*)(ws + 23 * N);      // 64x256
    ushort* W1t  = Wgt + 16384;                 // 256x64
    ushort* W2t  = W1t + 16384;                 // 256x256
    ushort* h0b  = (ushort*)(ws + 24 * N);      // [N,64] bf16
    float*  agg0 = ws + 56 * N;                 // [N,64] fp32
    ushort* h1b  = (ushort*)(ws + 120 * N);     // [N,256] bf16; also h2
    ushort* yb   = (ushort*)(ws + 376 * N);     // [N,256] bf16 gather out
    float*  outp = (float*)d_out;

    const int BLK = 256;
    dim3 blk(BLK);
    const int NBLK_N = (NN + 255) / 256;        // 391

    // ===== CSR build =====
    hipMemsetAsync(fill, 0, 2L * NN * sizeof(int), stream);
    hipMemsetAsync(sums0, 0, 1152 * sizeof(float), stream);
    hist_kernel<<<(EE + 255) / 256, blk, 0, stream>>>(ei, deg_i);
    scan_k1<<<NBLK_N, blk, 0, stream>>>(deg_i, row_start, bsum, dinv);
    scan_k2<<<1, 512, 0, stream>>>(bsum, NBLK_N);
    scan_k3<<<(NN + 1 + 255) / 256, blk, 0, stream>>>(row_start, bsum);
    scatter_kernel<<<(EE + NN + 255) / 256, blk, 0, stream>>>(ei, row_start, fill, sorted);

    // ===== weight conversions (one dispatch) =====
    transpose_all<<<(FIN * CH + CH * C1 + C1 * C1 + 255) / 256, blk, 0, stream>>>(
        W_gcn, W1, W2, Wgt, W1t, W2t);

    // ===== GCN =====
    gemm_mfma<1><<<dim3(1, (NN + 63) / 64), blk, 0, stream>>>(
        x, Wgt, h0b, FIN, CH, nullptr, nullptr, nullptr,
        nullptr, nullptr, nullptr, nullptr);
    gcn_gather<<<(NN + 3) / 4, blk, 0, stream>>>(row_start, sorted, dinv, h0b, agg0);
    bn_stats64<<<512, blk, 0, stream>>>(agg0, b_gcn, sums0, sumsq0);
    bn_finalize<<<1, CH, 0, stream>>>(sums0, sumsq0, g0, beta0, scale, shift, CH);

    // ===== GAT layer 1 (BN-apply fused into A-load; alpha fused) =====
    gemm_mfma<2><<<dim3(4, (NN + 63) / 64), blk, 0, stream>>>(
        agg0, W1t, h1b, CH, C1, b_gcn, scale, shift,
        a_src1, a_dst1, alpha_s, alpha_d);
    gat_gather<<<(NN + 3) / 4, blk, 0, stream>>>(row_start, sorted, alpha_s, alpha_d, h1b, yb);
    bn_stats256<<<512, blk, 0, stream>>>(yb, sums1, sumsq1);
    bn_finalize<<<1, C1, 0, stream>>>(sums1, sumsq1, g1, beta1, scale, shift, C1);

    // ===== GAT layer 2 (BN+ELU fused into A-load; alpha fused) =====
    gemm_mfma<3><<<dim3(4, (NN + 63) / 64), blk, 0, stream>>>(
        yb, W2t, h1b, C1, C1, nullptr, scale, shift,
        a_src2, a_dst2, alpha_s, alpha_d);
    gat_gather<<<(NN + 3) / 4, blk, 0, stream>>>(row_start, sorted, alpha_s, alpha_d, h1b, yb);
    bn_stats256<<<512, blk, 0, stream>>>(yb, sums2, sumsq2);
    bn_finalize<<<1, C1, 0, stream>>>(sums2, sumsq2, g2, beta2, scale, shift, C1);
    bn_apply_gat<<<2048, blk, 0, stream>>>(yb, scale, shift, outp);
}

// Round 14
// 783.220 us; speedup vs baseline: 1.0513x; 1.0051x over previous
//
#include <hip/hip_runtime.h>
#include <hip/hip_bf16.h>
#include <math.h>

#define NN 100000
#define EE 800000
#define FIN 256
#define CH 64      // HID
#define C1 256     // H*HID
#define BN_EPS 1e-5f
#define NEG_SLOPE 0.2f

typedef __attribute__((ext_vector_type(8))) short short8;
typedef __attribute__((ext_vector_type(8))) unsigned short u16x8;
typedef __attribute__((ext_vector_type(4))) float f32x4;

__device__ __forceinline__ float bf2f(ushort u) {
    return __uint_as_float(((unsigned)u) << 16);
}
__device__ __forceinline__ ushort f2bf(float f) {
    unsigned u = __float_as_uint(f);
    return (ushort)((u + 0x7FFF + ((u >> 16) & 1)) >> 16);   // RNE
}
__device__ __forceinline__ float hsel(f32x4 e, int head) {
    return (head & 2) ? ((head & 1) ? e[3] : e[2]) : ((head & 1) ? e[1] : e[0]);
}

// ================= CSR build =================
__global__ void hist_kernel(const int* __restrict__ ei, int* __restrict__ deg) {
    int t = blockIdx.x * 256 + threadIdx.x;
    if (t < EE) atomicAdd(&deg[ei[EE + t]], 1);
}
// scan over deg+1; also emits dinv = rsqrt(deg+1)
__global__ void scan_k1(const int* __restrict__ deg, int* __restrict__ row_start,
                        int* __restrict__ bsum, float* __restrict__ dinv) {
    __shared__ int sh[256];
    int t = threadIdx.x;
    int i = blockIdx.x * 256 + t;
    int v = (i < NN) ? (deg[i] + 1) : 0;
    if (i < NN) dinv[i] = rsqrtf((float)v);
    sh[t] = v;
    __syncthreads();
    for (int off = 1; off < 256; off <<= 1) {
        int add = (t >= off) ? sh[t - off] : 0;
        __syncthreads();
        sh[t] += add;
        __syncthreads();
    }
    if (i < NN) row_start[i] = sh[t] - v;
    if (t == 255) bsum[blockIdx.x] = sh[255];
}
__global__ void scan_k2(int* __restrict__ bsum, int nb) {
    __shared__ int sh[512];
    int t = threadIdx.x;
    int v = (t < nb) ? bsum[t] : 0;
    sh[t] = v;
    __syncthreads();
    for (int off = 1; off < 512; off <<= 1) {
        int add = (t >= off) ? sh[t - off] : 0;
        __syncthreads();
        sh[t] += add;
        __syncthreads();
    }
    if (t < nb) bsum[t] = sh[t] - v;
}
__global__ void scan_k3(int* __restrict__ row_start, const int* __restrict__ bsum) {
    int i = blockIdx.x * 256 + threadIdx.x;
    if (i < NN) row_start[i] += bsum[i >> 8];
    if (i == NN) row_start[NN] = EE + NN;
}
__global__ void scatter_kernel(const int* __restrict__ ei, const int* __restrict__ row_start,
                               int* __restrict__ fill, int* __restrict__ sorted) {
    int t = blockIdx.x * 256 + threadIdx.x;
    if (t >= EE + NN) return;
    int s, d;
    if (t < EE) { s = ei[t]; d = ei[EE + t]; }
    else        { s = t - EE; d = s; }
    int pos = atomicAdd(&fill[d], 1);
    sorted[row_start[d] + pos] = s;
}

// ================= weight conversions (all three in one dispatch) =========
__global__ void transpose_all(const float* __restrict__ Wg, const float* __restrict__ W1,
                              const float* __restrict__ W2, ushort* __restrict__ Wgt,
                              ushort* __restrict__ W1t, ushort* __restrict__ W2t) {
    int idx = blockIdx.x * 256 + threadIdx.x;
    if (idx < FIN * CH) {                       // Wg [FIN][CH] -> Wgt [CH][FIN]
        int m = idx / CH, n = idx % CH;
        Wgt[n * FIN + m] = f2bf(Wg[idx]);
    } else if (idx < FIN * CH + CH * C1) {      // W1 [CH][C1] -> W1t [C1][CH]
        int i = idx - FIN * CH;
        int m = i / C1, n = i % C1;
        W1t[n * CH + m] = f2bf(W1[i]);
    } else if (idx < FIN * CH + CH * C1 + C1 * C1) {
        int i = idx - FIN * CH - CH * C1;       // W2 [C1][C1] -> W2t [C1][C1]
        int m = i / C1, n = i % C1;
        W2t[n * C1 + m] = f2bf(W2[i]);
    }
}

// ====== bf16 MFMA GEMM (templated A-load, fused GAT alpha) ==
// C[N x K] = A[N x M] @ B[M x K]; Bt bf16 [K][M]. grid (K/64, N/64).
// AMODE 1: A fp32, plain convert (GEMM1).
// AMODE 2: A fp32 agg; value = bf16(scale*relu(a+bias)+shift)   (GCN BN apply)
// AMODE 3: A bf16 y;  value = bf16(elu(scale*y+shift))          (GAT BN apply)
// If alpha_s != null: col-block == head (K==256); fused alpha dot + store.
template<int AMODE>
__global__ __launch_bounds__(256) void gemm_mfma(
        const void* __restrict__ Ap, const ushort* __restrict__ Bt,
        ushort* __restrict__ C, int M, int K,
        const float* __restrict__ t_bias, const float* __restrict__ t_scale,
        const float* __restrict__ t_shift,
        const float* __restrict__ a_src, const float* __restrict__ a_dst,
        float* __restrict__ alpha_s, float* __restrict__ alpha_d) {
    __shared__ ushort As[64][40];
    __shared__ ushort Bs[64][40];
    int t = threadIdx.x;
    int w = t >> 6;
    int l = t & 63;
    int rowBase = blockIdx.y * 64;
    int colBase = blockIdx.x * 64;
    int srow = t >> 2;
    int sk = (t & 3) * 8;
    int m = l & 15, q = l >> 4;
    f32x4 acc[4] = {};
    for (int k0 = 0; k0 < M; k0 += 32) {
        int gr = rowBase + srow;
        int ch = k0 + sk;
        ushort4 u0 = {0, 0, 0, 0}, u1 = {0, 0, 0, 0};
        if (AMODE == 1) {
            if (gr < NN) {
                const float* Af = (const float*)Ap;
                float4 f0 = *(const float4*)&Af[(long)gr * M + ch];
                float4 f1 = *(const float4*)&Af[(long)gr * M + ch + 4];
                u0.x = f2bf(f0.x); u0.y = f2bf(f0.y); u0.z = f2bf(f0.z); u0.w = f2bf(f0.w);
                u1.x = f2bf(f1.x); u1.y = f2bf(f1.y); u1.z = f2bf(f1.z); u1.w = f2bf(f1.w);
            }
        } else if (AMODE == 2) {
            if (gr < NN) {
                const float* Af = (const float*)Ap;
                float4 f0 = *(const float4*)&Af[(long)gr * M + ch];
                float4 f1 = *(const float4*)&Af[(long)gr * M + ch + 4];
                f32x4 b0 = *(const f32x4*)&t_bias[ch],  b1 = *(const f32x4*)&t_bias[ch + 4];
                f32x4 s0 = *(const f32x4*)&t_scale[ch], s1 = *(const f32x4*)&t_scale[ch + 4];
                f32x4 h0 = *(const f32x4*)&t_shift[ch], h1 = *(const f32x4*)&t_shift[ch + 4];
                u0.x = f2bf(s0[0] * fmaxf(f0.x + b0[0], 0.f) + h0[0]);
                u0.y = f2bf(s0[1] * fmaxf(f0.y + b0[1], 0.f) + h0[1]);
                u0.z = f2bf(s0[2] * fmaxf(f0.z + b0[2], 0.f) + h0[2]);
                u0.w = f2bf(s0[3] * fmaxf(f0.w + b0[3], 0.f) + h0[3]);
                u1.x = f2bf(s1[0] * fmaxf(f1.x + b1[0], 0.f) + h1[0]);
                u1.y = f2bf(s1[1] * fmaxf(f1.y + b1[1], 0.f) + h1[1]);
                u1.z = f2bf(s1[2] * fmaxf(f1.z + b1[2], 0.f) + h1[2]);
                u1.w = f2bf(s1[3] * fmaxf(f1.w + b1[3], 0.f) + h1[3]);
            }
        } else { // AMODE == 3
            if (gr < NN) {
                const ushort* Ab = (const ushort*)Ap;
                u16x8 y = *(const u16x8*)&Ab[(long)gr * M + ch];
                f32x4 s0 = *(const f32x4*)&t_scale[ch], s1 = *(const f32x4*)&t_scale[ch + 4];
                f32x4 h0 = *(const f32x4*)&t_shift[ch], h1 = *(const f32x4*)&t_shift[ch + 4];
                float r[8];
#pragma unroll
                for (int j = 0; j < 8; ++j) {
                    float sc = (j < 4) ? s0[j] : s1[j - 4];
                    float sh = (j < 4) ? h0[j] : h1[j - 4];
                    float v = sc * bf2f((ushort)y[j]) + sh;
                    r[j] = (v > 0.f) ? v : (__expf(v) - 1.f);
                }
                u0.x = f2bf(r[0]); u0.y = f2bf(r[1]); u0.z = f2bf(r[2]); u0.w = f2bf(r[3]);
                u1.x = f2bf(r[4]); u1.y = f2bf(r[5]); u1.z = f2bf(r[6]); u1.w = f2bf(r[7]);
            }
        }
        *(ushort4*)&As[srow][sk] = u0;
        *(ushort4*)&As[srow][sk + 4] = u1;
        uint4 bv = *(const uint4*)&Bt[(long)(colBase + srow) * M + k0 + sk];
        *(uint4*)&Bs[srow][sk] = bv;
        __syncthreads();
        short8 af = *(const short8*)&As[w * 16 + m][q * 8];
#pragma unroll
        for (int c = 0; c < 4; ++c) {
            short8 bf = *(const short8*)&Bs[c * 16 + m][q * 8];
            acc[c] = __builtin_amdgcn_mfma_f32_16x16x32_bf16(af, bf, acc[c], 0, 0, 0);
        }
        __syncthreads();
    }
    if (alpha_s) {
        int head = colBase >> 6;
        float ps[4] = {}, pd[4] = {};
#pragma unroll
        for (int c = 0; c < 4; ++c) {
            float av = a_src[colBase + c * 16 + m];
            float dv = a_dst[colBase + c * 16 + m];
#pragma unroll
            for (int r = 0; r < 4; ++r) {
                ps[r] += acc[c][r] * av;
                pd[r] += acc[c][r] * dv;
            }
        }
#pragma unroll
        for (int r = 0; r < 4; ++r) {
            ps[r] += __shfl_xor(ps[r], 1); pd[r] += __shfl_xor(pd[r], 1);
            ps[r] += __shfl_xor(ps[r], 2); pd[r] += __shfl_xor(pd[r], 2);
            ps[r] += __shfl_xor(ps[r], 4); pd[r] += __shfl_xor(pd[r], 4);
            ps[r] += __shfl_xor(ps[r], 8); pd[r] += __shfl_xor(pd[r], 8);
        }
        if (m == 0) {
#pragma unroll
            for (int r = 0; r < 4; ++r) {
                int row = rowBase + w * 16 + q * 4 + r;
                if (row < NN) {
                    alpha_s[row * 4 + head] = ps[r];
                    alpha_d[row * 4 + head] = pd[r];
                }
            }
        }
    }
#pragma unroll
    for (int c = 0; c < 4; ++c) {
#pragma unroll
        for (int r = 0; r < 4; ++r) {
            int orow = rowBase + w * 16 + q * 4 + r;
            if (orow < NN) C[(long)orow * K + colBase + c * 16 + m] = f2bf(acc[c][r]);
        }
    }
}

// ================= GCN gather =================
__global__ __launch_bounds__(256) void gcn_gather(
        const int* __restrict__ row_start, const int* __restrict__ sorted,
        const float* __restrict__ dinv, const ushort* __restrict__ h0,
        float* __restrict__ agg) {
    int node = __builtin_amdgcn_readfirstlane(blockIdx.x * 4 + (threadIdx.x >> 6));
    if (node >= NN) return;
    int l = threadIdx.x & 63;
    int slot = l >> 3;          // edge slot 0..7
    int li = l & 7;             // lane within row
    int c = li * 8;             // 8 channels of 64
    int b = row_start[node], e = row_start[node + 1];
    float a[8] = {};
    for (int i = b + slot; i < e; i += 8) {
        int s = sorted[i];
        float dv = dinv[s];
        u16x8 v = *(const u16x8*)&h0[(long)s * 64 + c];
#pragma unroll
        for (int j = 0; j < 8; ++j) a[j] += dv * bf2f((ushort)v[j]);
    }
#pragma unroll
    for (int j = 0; j < 8; ++j) {
        a[j] += __shfl_xor(a[j], 8);
        a[j] += __shfl_xor(a[j], 16);
        a[j] += __shfl_xor(a[j], 32);
    }
    if (slot == 0) {
        float dn = dinv[node];
        f32x4 o0, o1;
#pragma unroll
        for (int j = 0; j < 4; ++j) { o0[j] = a[j] * dn; o1[j] = a[4 + j] * dn; }
        *(f32x4*)&agg[(long)node * 64 + c] = o0;
        *(f32x4*)&agg[(long)node * 64 + c + 4] = o1;
    }
}

// ================= BatchNorm =================
__global__ __launch_bounds__(256) void bn_stats64(
        const float* __restrict__ x, const float* __restrict__ bias,
        float* __restrict__ sums, float* __restrict__ sumsq) {
    __shared__ float red[4][16][8];
    int l = threadIdx.x & 63;
    int w = threadIdx.x >> 6;
    int wv = blockIdx.x * 4 + w;
    int nw = gridDim.x * 4;
    int sub = l >> 4;
    int c = (l & 15) * 4;
    f32x4 b4 = *(const f32x4*)&bias[c];
    float s0 = 0.f, s1 = 0.f, s2 = 0.f, s3 = 0.f;
    float q0 = 0.f, q1 = 0.f, q2 = 0.f, q3 = 0.f;
    for (int r = wv * 4 + sub; r < NN; r += nw * 4) {
        f32x4 v = *(const f32x4*)&x[(long)r * 64 + c];
        float v0 = fmaxf(v[0] + b4[0], 0.f);
        float v1 = fmaxf(v[1] + b4[1], 0.f);
        float v2 = fmaxf(v[2] + b4[2], 0.f);
        float v3 = fmaxf(v[3] + b4[3], 0.f);
        s0 += v0; s1 += v1; s2 += v2; s3 += v3;
        q0 += v0 * v0; q1 += v1 * v1; q2 += v2 * v2; q3 += v3 * v3;
    }
    s0 += __shfl_xor(s0, 16); s1 += __shfl_xor(s1, 16);
    s2 += __shfl_xor(s2, 16); s3 += __shfl_xor(s3, 16);
    q0 += __shfl_xor(q0, 16); q1 += __shfl_xor(q1, 16);
    q2 += __shfl_xor(q2, 16); q3 += __shfl_xor(q3, 16);
    s0 += __shfl_xor(s0, 32); s1 += __shfl_xor(s1, 32);
    s2 += __shfl_xor(s2, 32); s3 += __shfl_xor(s3, 32);
    q0 += __shfl_xor(q0, 32); q1 += __shfl_xor(q1, 32);
    q2 += __shfl_xor(q2, 32); q3 += __shfl_xor(q3, 32);
    if (sub == 0) {
        int li = l & 15;
        red[w][li][0] = s0; red[w][li][1] = s1; red[w][li][2] = s2; red[w][li][3] = s3;
        red[w][li][4] = q0; red[w][li][5] = q1; red[w][li][6] = q2; red[w][li][7] = q3;
    }
    __syncthreads();
    if (w == 0 && sub == 0) {
        int li = l & 15;
        atomicAdd(&sums[c + 0], red[0][li][0] + red[1][li][0] + red[2][li][0] + red[3][li][0]);
        atomicAdd(&sums[c + 1], red[0][li][1] + red[1][li][1] + red[2][li][1] + red[3][li][1]);
        atomicAdd(&sums[c + 2], red[0][li][2] + red[1][li][2] + red[2][li][2] + red[3][li][2]);
        atomicAdd(&sums[c + 3], red[0][li][3] + red[1][li][3] + red[2][li][3] + red[3][li][3]);
        atomicAdd(&sumsq[c + 0], red[0][li][4] + red[1][li][4] + red[2][li][4] + red[3][li][4]);
        atomicAdd(&sumsq[c + 1], red[0][li][5] + red[1][li][5] + red[2][li][5] + red[3][li][5]);
        atomicAdd(&sumsq[c + 2], red[0][li][6] + red[1][li][6] + red[2][li][6] + red[3][li][6]);
        atomicAdd(&sumsq[c + 3], red[0][li][7] + red[1][li][7] + red[2][li][7] + red[3][li][7]);
    }
}
__global__ __launch_bounds__(256) void bn_stats256(
        const ushort* __restrict__ x,
        float* __restrict__ sums, float* __restrict__ sumsq) {
    __shared__ float red[4][64][8];
    int l = threadIdx.x & 63;
    int w = threadIdx.x >> 6;
    int wv = blockIdx.x * 4 + w;
    int nw = gridDim.x * 4;
    int c = l * 4;
    float s0 = 0.f, s1 = 0.f, s2 = 0.f, s3 = 0.f;
    float q0 = 0.f, q1 = 0.f, q2 = 0.f, q3 = 0.f;
    for (int r = wv; r < NN; r += nw) {
        ushort4 v = *(const ushort4*)&x[(long)r * 256 + c];
        float v0 = bf2f(v.x), v1 = bf2f(v.y), v2 = bf2f(v.z), v3 = bf2f(v.w);
        s0 += v0; s1 += v1; s2 += v2; s3 += v3;
        q0 += v0 * v0; q1 += v1 * v1; q2 += v2 * v2; q3 += v3 * v3;
    }
    red[w][l][0] = s0; red[w][l][1] = s1; red[w][l][2] = s2; red[w][l][3] = s3;
    red[w][l][4] = q0; red[w][l][5] = q1; red[w][l][6] = q2; red[w][l][7] = q3;
    __syncthreads();
    if (w == 0) {
        atomicAdd(&sums[c + 0], red[0][l][0] + red[1][l][0] + red[2][l][0] + red[3][l][0]);
        atomicAdd(&sums[c + 1], red[0][l][1] + red[1][l][1] + red[2][l][1] + red[3][l][1]);
        atomicAdd(&sums[c + 2], red[0][l][2] + red[1][l][2] + red[2][l][2] + red[3][l][2]);
        atomicAdd(&sums[c + 3], red[0][l][3] + red[1][l][3] + red[2][l][3] + red[3][l][3]);
        atomicAdd(&sumsq[c + 0], red[0][l][4] + red[1][l][4] + red[2][l][4] + red[3][l][4]);
        atomicAdd(&sumsq[c + 1], red[0][l][5] + red[1][l][5] + red[2][l][5] + red[3][l][5]);
        atomicAdd(&sumsq[c + 2], red[0][l][6] + red[1][l][6] + red[2][l][6] + red[3][l][6]);
        atomicAdd(&sumsq[c + 3], red[0][l][7] + red[1][l][7] + red[2][l][7] + red[3][l][7]);
    }
}
__global__ void bn_finalize(const float* __restrict__ sums, const float* __restrict__ sumsq,
                            const float* __restrict__ g, const float* __restrict__ beta,
                            float* __restrict__ scale, float* __restrict__ shift, int C) {
    int c = threadIdx.x;
    if (c < C) {
        float mean = sums[c] / (float)NN;
        float var = sumsq[c] / (float)NN - mean * mean;
        float sc = g[c] * rsqrtf(var + BN_EPS);
        scale[c] = sc;
        shift[c] = beta[c] - mean * sc;
    }
}
// GAT BN apply, fp32 out (final layer only; bias cancels).
__global__ __launch_bounds__(256) void bn_apply_gat(
        const ushort* __restrict__ x,
        const float* __restrict__ scale, const float* __restrict__ shift,
        float* __restrict__ out) {
    int l = threadIdx.x & 63;
    int wv = blockIdx.x * 4 + (threadIdx.x >> 6);
    int nw = gridDim.x * 4;
    int c = l * 4;
    f32x4 sc4 = *(const f32x4*)&scale[c];
    f32x4 sh4 = *(const f32x4*)&shift[c];
    for (int r = wv; r < NN; r += nw) {
        ushort4 v = *(const ushort4*)&x[(long)r * 256 + c];
        float t0 = sc4[0] * bf2f(v.x) + sh4[0];
        float t1 = sc4[1] * bf2f(v.y) + sh4[1];
        float t2 = sc4[2] * bf2f(v.z) + sh4[2];
        float t3 = sc4[3] * bf2f(v.w) + sh4[3];
        f32x4 o;
        o[0] = (t0 > 0.f) ? t0 : (__expf(t0) - 1.f);
        o[1] = (t1 > 0.f) ? t1 : (__expf(t1) - 1.f);
        o[2] = (t2 > 0.f) ? t2 : (__expf(t2) - 1.f);
        o[3] = (t3 > 0.f) ? t3 : (__expf(t3) - 1.f);
        *(f32x4*)&out[(long)r * 256 + c] = o;
    }
}

// ========== FUSED GAT attention+gather (scalarized + 8-deep MLP) ==========
// One WAVE per node. sorted[i]/as rows via SMEM pipe (uniform); h-rows via
// VMEM. 8-edge main stage doubles in-flight row fetches vs round 13.
__global__ __launch_bounds__(256) void gat_gather(
        const int* __restrict__ row_start, const int* __restrict__ sorted,
        const float* __restrict__ as, const float* __restrict__ ad,
        const ushort* __restrict__ h, ushort* __restrict__ out) {
    int node = __builtin_amdgcn_readfirstlane(blockIdx.x * 4 + (threadIdx.x >> 6));
    if (node >= NN) return;
    int l = threadIdx.x & 63;
    int head = l >> 4;                      // channels 4l..4l+3 share one head
    int b = row_start[node], e = row_start[node + 1];   // uniform -> s_load
    f32x4 ad4 = *(const f32x4*)&ad[node * 4];           // uniform -> s_load x4
    float adn = hsel(ad4, head);
    float a0 = 0.f, a1 = 0.f, a2 = 0.f, a3 = 0.f;
    float ls = 0.f;
    int i = b;
    for (; i + 7 < e; i += 8) {
        int s[8];
#pragma unroll
        for (int j = 0; j < 8; ++j) s[j] = sorted[i + j];        // s_load
        f32x4 ev[8];
#pragma unroll
        for (int j = 0; j < 8; ++j) ev[j] = *(const f32x4*)&as[s[j] * 4];  // s_load_dwordx4
        ushort4 v[8];
#pragma unroll
        for (int j = 0; j < 8; ++j) v[j] = *(const ushort4*)&h[(long)s[j] * 256 + l * 4];
        float wt[8];
#pragma unroll
        for (int j = 0; j < 8; ++j) {
            float tt = hsel(ev[j], head) + adn;
            tt = (tt > 0.f) ? tt : NEG_SLOPE * tt;
            wt[j] = __expf(tt);
            ls += wt[j];
        }
#pragma unroll
        for (int j = 0; j < 8; ++j) {
            a0 += wt[j] * bf2f(v[j].x);
            a1 += wt[j] * bf2f(v[j].y);
            a2 += wt[j] * bf2f(v[j].z);
            a3 += wt[j] * bf2f(v[j].w);
        }
    }
    if (i + 3 < e) {
        int s[4];
#pragma unroll
        for (int j = 0; j < 4; ++j) s[j] = sorted[i + j];
        f32x4 ev[4];
#pragma unroll
        for (int j = 0; j < 4; ++j) ev[j] = *(const f32x4*)&as[s[j] * 4];
        ushort4 v[4];
#pragma unroll
        for (int j = 0; j < 4; ++j) v[j] = *(const ushort4*)&h[(long)s[j] * 256 + l * 4];
#pragma unroll
        for (int j = 0; j < 4; ++j) {
            float tt = hsel(ev[j], head) + adn;
            tt = (tt > 0.f) ? tt : NEG_SLOPE * tt;
            float wt = __expf(tt);
            ls += wt;
            a0 += wt * bf2f(v[j].x);
            a1 += wt * bf2f(v[j].y);
            a2 += wt * bf2f(v[j].z);
            a3 += wt * bf2f(v[j].w);
        }
        i += 4;
    }
    for (; i < e; ++i) {
        int sv = sorted[i];
        f32x4 e0 = *(const f32x4*)&as[sv * 4];
        float tt = hsel(e0, head) + adn;
        tt = (tt > 0.f) ? tt : NEG_SLOPE * tt;
        float wt = __expf(tt);
        ushort4 v0 = *(const ushort4*)&h[(long)sv * 256 + l * 4];
        ls += wt;
        a0 += wt * bf2f(v0.x);
        a1 += wt * bf2f(v0.y);
        a2 += wt * bf2f(v0.z);
        a3 += wt * bf2f(v0.w);
    }
    float inv = 1.0f / ls;
    ushort4 o;
    o.x = f2bf(a0 * inv);
    o.y = f2bf(a1 * inv);
    o.z = f2bf(a2 * inv);
    o.w = f2bf(a3 * inv);
    *(ushort4*)&out[(long)node * 256 + l * 4] = o;
}

// ================= launch =================
extern "C" void kernel_launch(void* const* d_in, const int* in_sizes, int n_in,
                              void* d_out, int out_size, void* d_ws, size_t ws_size,
                              hipStream_t stream) {
    const float* x      = (const float*)d_in[0];
    const int*   ei     = (const int*)d_in[1];
    const float* W_gcn  = (const float*)d_in[2];
    const float* b_gcn  = (const float*)d_in[3];
    const float* g0     = (const float*)d_in[4];
    const float* beta0  = (const float*)d_in[5];
    const float* W1     = (const float*)d_in[6];
    const float* a_src1 = (const float*)d_in[7];
    const float* a_dst1 = (const float*)d_in[8];
    const float* b1     = (const float*)d_in[9];
    const float* g1     = (const float*)d_in[10];
    const float* beta1  = (const float*)d_in[11];
    const float* W2     = (const float*)d_in[12];
    const float* a_src2 = (const float*)d_in[13];
    const float* a_dst2 = (const float*)d_in[14];
    const float* b2     = (const float*)d_in[15];
    const float* g2     = (const float*)d_in[16];
    const float* beta2  = (const float*)d_in[17];

    const long N = NN;
    float* ws = (float*)d_ws;

    // ---- layout ----
    float* dinv    = ws;                        // N
    float* alpha_s = ws + N;                    // 4N
    float* alpha_d = ws + 5 * N;                // 4N
    float* sums0   = ws + 9 * N;                // 64
    float* sumsq0  = sums0 + 64;                // 64
    float* sums1   = sumsq0 + 64;               // 256
    float* sumsq1  = sums1 + 256;               // 256
    float* sums2   = sumsq1 + 256;              // 256
    float* sumsq2  = sums2 + 256;               // 256  (stats region = 1152 floats)
    float* scale   = sumsq2 + 256;              // 256
    float* shift   = scale + 256;               // 256
    int*   row_start = (int*)(shift + 256);     // N+1
    int*   fill      = row_start + NN + 1;      // N
    int*   deg_i     = fill + NN;               // N
    int*   sorted    = deg_i + NN;              // 9N
    int*   bsum      = sorted + EE + NN;        // ~400
    ushort* Wgt  = (ushort*)(ws + 23 * N);      // 64x256
    ushort* W1t  = Wgt + 16384;                 // 256x64
    ushort* W2t  = W1t + 16384;                 // 256x256
    ushort* h0b  = (ushort*)(ws + 24 * N);      // [N,64] bf16
    float*  agg0 = ws + 56 * N;                 // [N,64] fp32
    ushort* h1b  = (ushort*)(ws + 120 * N);     // [N,256] bf16; also h2
    ushort* yb   = (ushort*)(ws + 376 * N);     // [N,256] bf16 gather out
    float*  outp = (float*)d_out;

    const int BLK = 256;
    dim3 blk(BLK);
    const int NBLK_N = (NN + 255) / 256;        // 391

    // ===== CSR build =====
    hipMemsetAsync(fill, 0, 2L * NN * sizeof(int), stream);
    hipMemsetAsync(sums0, 0, 1152 * sizeof(float), stream);
    hist_kernel<<<(EE + 255) / 256, blk, 0, stream>>>(ei, deg_i);
    scan_k1<<<NBLK_N, blk, 0, stream>>>(deg_i, row_start, bsum, dinv);
    scan_k2<<<1, 512, 0, stream>>>(bsum, NBLK_N);
    scan_k3<<<(NN + 1 + 255) / 256, blk, 0, stream>>>(row_start, bsum);
    scatter_kernel<<<(EE + NN + 255) / 256, blk, 0, stream>>>(ei, row_start, fill, sorted);

    // ===== weight conversions (one dispatch) =====
    transpose_all<<<(FIN * CH + CH * C1 + C1 * C1 + 255) / 256, blk, 0, stream>>>(
        W_gcn, W1, W2, Wgt, W1t, W2t);

    // ===== GCN =====
    gemm_mfma<1><<<dim3(1, (NN + 63) / 64), blk, 0, stream>>>(
        x, Wgt, h0b, FIN, CH, nullptr, nullptr, nullptr,
        nullptr, nullptr, nullptr, nullptr);
    gcn_gather<<<(NN + 3) / 4, blk, 0, stream>>>(row_start, sorted, dinv, h0b, agg0);
    bn_stats64<<<512, blk, 0, stream>>>(agg0, b_gcn, sums0, sumsq0);
    bn_finalize<<<1, CH, 0, stream>>>(sums0, sumsq0, g0, beta0, scale, shift, CH);

    // ===== GAT layer 1 (BN-apply fused into A-load; alpha fused) =====
    gemm_mfma<2><<<dim3(4, (NN + 63) / 64), blk, 0, stream>>>(
        agg0, W1t, h1b, CH, C1, b_gcn, scale, shift,
        a_src1, a_dst1, alpha_s, alpha_d);
    gat_gather<<<(NN + 3) / 4, blk, 0, stream>>>(row_start, sorted, alpha_s, alpha_d, h1b, yb);
    bn_stats256<<<512, blk, 0, stream>>>(yb, sums1, sumsq1);
    bn_finalize<<<1, C1, 0, stream>>>(sums1, sumsq1, g1, beta1, scale, shift, C1);

    // ===== GAT layer 2 (BN+ELU fused into A-load; alpha fused) =====
    gemm_mfma<3><<<dim3(4, (NN + 63) / 64), blk, 0, stream>>>(
        yb, W2t, h1b, C1, C1, nullptr, scale, shift,
        a_src2, a_dst2, alpha_s, alpha_d);
    gat_gather<<<(NN + 3) / 4, blk, 0, stream>>>(row_start, sorted, alpha_s, alpha_d, h1b, yb);
    bn_stats256<<<512, blk, 0, stream>>>(yb, sums2, sumsq2);
    bn_finalize<<<1, C1, 0, stream>>>(sums2, sumsq2, g2, beta2, scale, shift, C1);
    bn_apply_gat<<<2048, blk, 0, stream>>>(yb, scale, shift, outp);
}